// Round 1
// baseline (360.603 us; speedup 1.0000x reference)
//
#include <hip/hip_runtime.h>
#include <hip/hip_bf16.h>

// AngularMarginLoss: B=2048, D=256, C=100000
// loss = -mean_b( num_b - log(exp(num_b) + sum_{c!=t_b} exp(30*cos_bc) + 1e-6) )
// num_b = 30*cos(acos(clip(cos_bt)) + 0.2)

static constexpr int Bn = 2048;
static constexpr int Dn = 256;
static constexpr int Cn = 100000;
static constexpr int COLS_PER_BLOCK = 128;                       // 2 waves x 4 tiles x 16
static constexpr int NBLK = (Cn + COLS_PER_BLOCK - 1) / COLS_PER_BLOCK;  // 782
// OOB padded columns contribute exp(0)=1 each to every row sum; subtract at the end.
static constexpr float OOB_COLS = (float)(NBLK * COLS_PER_BLOCK - Cn);   // 96

#define SCALE_F 30.0f
#define MARGIN_F 0.2f
#define EPS_F 1e-6f

typedef __attribute__((ext_vector_type(8))) short bf16x8;   // 8 bf16 = 4 VGPRs
typedef __attribute__((ext_vector_type(4))) float f32x4;

__device__ __forceinline__ short f2bf_rne(float x) {
    union { float f; unsigned int u; } v; v.f = x;
    unsigned int r = v.u + 0x7fffu + ((v.u >> 16) & 1u);
    return (short)(r >> 16);
}

// ---- kernel 1: emb fp32 -> bf16 (row-major, 2048x256) ----
__global__ __launch_bounds__(256) void k_emb2bf(const float* __restrict__ emb,
                                                short* __restrict__ out) {
    int i = (blockIdx.x * 256 + threadIdx.x) * 4;   // 512 blocks covers 524288 exactly
    float4 x = *(const float4*)(emb + i);
    short4 o;
    o.x = f2bf_rne(x.x); o.y = f2bf_rne(x.y);
    o.z = f2bf_rne(x.z); o.w = f2bf_rne(x.w);
    *(short4*)(out + i) = o;
}

// ---- kernel 2: main fused GEMM + exp row-sum ----
// Block: 128 threads (2 waves). Each wave owns 64 classes (4 MFMA col-tiles of 16),
// W rows normalized+bf16-converted once into persistent A-fragments (128 VGPRs),
// then streams all 2048 samples in 16-row tiles through LDS.
__global__ __launch_bounds__(128, 2) void k_main(const float* __restrict__ W,
                                                 const short* __restrict__ embbf,
                                                 float* __restrict__ rowsum) {
    __shared__ __align__(16) short stage[16 * 264];   // 16 emb rows, stride 264 (pad 8)
    __shared__ float rowAccum[Bn];                    // per-block partial row sums

    const int tid  = threadIdx.x;
    const int wave = tid >> 6;
    const int lane = tid & 63;
    const int q    = lane >> 4;   // quad 0..3
    const int cr   = lane & 15;
    const int cbase = blockIdx.x * COLS_PER_BLOCK + wave * 64;

    for (int i = tid; i < Bn; i += 128) rowAccum[i] = 0.0f;

    // ---- prologue: normalized bf16 A-fragments for 4 col-tiles ----
    // A layout (16x16x32): lane holds A[m=lane&15][k = q*8 + j] per 32-wide k-step.
    bf16x8 afrag[4][8];
#pragma unroll
    for (int ct = 0; ct < 4; ++ct) {
        const int c = cbase + ct * 16 + cr;
        float wtmp[64];
        float ss = 0.0f;
        if (c < Cn) {
            const float* wr = W + (long)c * Dn;
#pragma unroll
            for (int ks = 0; ks < 8; ++ks) {
                float4 x0 = *(const float4*)(wr + ks * 32 + q * 8);
                float4 x1 = *(const float4*)(wr + ks * 32 + q * 8 + 4);
                wtmp[ks * 8 + 0] = x0.x; wtmp[ks * 8 + 1] = x0.y;
                wtmp[ks * 8 + 2] = x0.z; wtmp[ks * 8 + 3] = x0.w;
                wtmp[ks * 8 + 4] = x1.x; wtmp[ks * 8 + 5] = x1.y;
                wtmp[ks * 8 + 6] = x1.z; wtmp[ks * 8 + 7] = x1.w;
                ss += x0.x * x0.x + x0.y * x0.y + x0.z * x0.z + x0.w * x0.w;
                ss += x1.x * x1.x + x1.y * x1.y + x1.z * x1.z + x1.w * x1.w;
            }
        } else {
#pragma unroll
            for (int j = 0; j < 64; ++j) wtmp[j] = 0.0f;
        }
        // lanes {cr, cr+16, cr+32, cr+48} each hold 64 distinct elements of row c
        ss += __shfl_xor(ss, 16);
        ss += __shfl_xor(ss, 32);
        const float rn = 1.0f / fmaxf(sqrtf(ss), 1e-12f);
#pragma unroll
        for (int ks = 0; ks < 8; ++ks) {
            bf16x8 a;
#pragma unroll
            for (int j = 0; j < 8; ++j) a[j] = f2bf_rne(wtmp[ks * 8 + j] * rn);
            afrag[ct][ks] = a;
        }
    }

    __syncthreads();

    // ---- stream over sample row-tiles ----
    for (int rt = 0; rt < Bn / 16; ++rt) {
        // stage emb rows rt*16..+15 into LDS (contiguous 8KB from global)
        {
            const int r  = tid >> 3;          // 0..15
            const int cc = (tid & 7) * 32;    // 8 threads x 32 shorts = 256
            const short* src = embbf + (rt * 16 + r) * Dn + cc;
            short* dst = stage + r * 264 + cc;
            *(bf16x8*)(dst)      = *(const bf16x8*)(src);
            *(bf16x8*)(dst + 8)  = *(const bf16x8*)(src + 8);
            *(bf16x8*)(dst + 16) = *(const bf16x8*)(src + 16);
            *(bf16x8*)(dst + 24) = *(const bf16x8*)(src + 24);
        }
        __syncthreads();

        // B layout: lane holds B[k = q*8 + j][n = lane&15], B[k][n] = emb[rt*16+n][k]
        bf16x8 bfrag[8];
#pragma unroll
        for (int ks = 0; ks < 8; ++ks)
            bfrag[ks] = *(const bf16x8*)(stage + cr * 264 + ks * 32 + q * 8);

        f32x4 acc0 = {0.f, 0.f, 0.f, 0.f};
        f32x4 acc1 = {0.f, 0.f, 0.f, 0.f};
        f32x4 acc2 = {0.f, 0.f, 0.f, 0.f};
        f32x4 acc3 = {0.f, 0.f, 0.f, 0.f};
#pragma unroll
        for (int ks = 0; ks < 8; ++ks) {
            acc0 = __builtin_amdgcn_mfma_f32_16x16x32_bf16(afrag[0][ks], bfrag[ks], acc0, 0, 0, 0);
            acc1 = __builtin_amdgcn_mfma_f32_16x16x32_bf16(afrag[1][ks], bfrag[ks], acc1, 0, 0, 0);
            acc2 = __builtin_amdgcn_mfma_f32_16x16x32_bf16(afrag[2][ks], bfrag[ks], acc2, 0, 0, 0);
            acc3 = __builtin_amdgcn_mfma_f32_16x16x32_bf16(afrag[3][ks], bfrag[ks], acc3, 0, 0, 0);
        }

        // D layout: col = lane&15 = sample, row = q*4+reg = class. Sum exp over classes.
        float s = 0.0f;
#pragma unroll
        for (int r = 0; r < 4; ++r) {
            s += __expf(SCALE_F * fminf(fmaxf(acc0[r], -1.f), 1.f));
            s += __expf(SCALE_F * fminf(fmaxf(acc1[r], -1.f), 1.f));
            s += __expf(SCALE_F * fminf(fmaxf(acc2[r], -1.f), 1.f));
            s += __expf(SCALE_F * fminf(fmaxf(acc3[r], -1.f), 1.f));
        }
        s += __shfl_xor(s, 16);
        s += __shfl_xor(s, 32);
        if (lane < 16) atomicAdd(&rowAccum[rt * 16 + lane], s);
        __syncthreads();   // protect stage before next overwrite
    }

    for (int i = tid; i < Bn; i += 128) atomicAdd(&rowsum[i], rowAccum[i]);
}

// ---- kernel 3: per-sample target cosine (fp32) ----
__global__ __launch_bounds__(256) void k_target(const float* __restrict__ emb,
                                                const float* __restrict__ W,
                                                const int* __restrict__ tgt,
                                                float* __restrict__ numv,
                                                float* __restrict__ etv) {
    const int b = blockIdx.x;
    const int t = tgt[b];
    const float x = W[(long)t * Dn + threadIdx.x];
    const float e = emb[b * Dn + threadIdx.x];
    float dot = x * e;
    float ss  = x * x;
#pragma unroll
    for (int o = 1; o < 64; o <<= 1) {
        dot += __shfl_xor(dot, o);
        ss  += __shfl_xor(ss, o);
    }
    __shared__ float sd[4], sq[4];
    const int wave = threadIdx.x >> 6, lane = threadIdx.x & 63;
    if (lane == 0) { sd[wave] = dot; sq[wave] = ss; }
    __syncthreads();
    if (threadIdx.x == 0) {
        const float d  = sd[0] + sd[1] + sd[2] + sd[3];
        const float s2 = sq[0] + sq[1] + sq[2] + sq[3];
        float cosv = d / fmaxf(sqrtf(s2), 1e-12f);
        cosv = fminf(fmaxf(cosv, -1.f), 1.f);
        const float num = SCALE_F * cosf(acosf(cosv) + MARGIN_F);
        numv[b] = num;
        etv[b]  = __expf(SCALE_F * cosv);
    }
}

// ---- kernel 4: final loss reduction ----
__global__ __launch_bounds__(256) void k_loss(const float* __restrict__ numv,
                                              const float* __restrict__ etv,
                                              const float* __restrict__ rowsum,
                                              float* __restrict__ out) {
    float acc = 0.0f;
    for (int b = threadIdx.x; b < Bn; b += 256) {
        const float num  = numv[b];
        const float excl = rowsum[b] - OOB_COLS - etv[b];   // drop padding + target column
        const float denom = __expf(num) + excl;
        acc += num - logf(denom + EPS_F);
    }
#pragma unroll
    for (int o = 1; o < 64; o <<= 1) acc += __shfl_xor(acc, o);
    __shared__ float sa[4];
    const int wave = threadIdx.x >> 6, lane = threadIdx.x & 63;
    if (lane == 0) sa[wave] = acc;
    __syncthreads();
    if (threadIdx.x == 0) out[0] = -(sa[0] + sa[1] + sa[2] + sa[3]) / (float)Bn;
}

extern "C" void kernel_launch(void* const* d_in, const int* in_sizes, int n_in,
                              void* d_out, int out_size, void* d_ws, size_t ws_size,
                              hipStream_t stream) {
    const float* emb = (const float*)d_in[0];   // 2048*256
    const float* W   = (const float*)d_in[1];   // 100000*256
    const int*   tgt = (const int*)d_in[2];     // 2048
    float* out = (float*)d_out;

    char* ws = (char*)d_ws;
    short* embbf  = (short*)ws;                     // 1 MB
    float* rowsum = (float*)(ws + (1 << 20));       // 8 KB
    float* numv   = rowsum + Bn;                    // 8 KB
    float* etv    = numv + Bn;                      // 8 KB

    hipMemsetAsync(rowsum, 0, Bn * sizeof(float), stream);
    k_emb2bf<<<512, 256, 0, stream>>>(emb, embbf);
    k_main<<<NBLK, 128, 0, stream>>>(W, embbf, rowsum);
    k_target<<<Bn, 256, 0, stream>>>(emb, W, tgt, numv, etv);
    k_loss<<<1, 256, 0, stream>>>(numv, etv, rowsum, out);
}